// Round 1
// baseline (358.044 us; speedup 1.0000x reference)
//
#include <hip/hip_runtime.h>
#include <hip/hip_bf16.h>
#include <math.h>

// Problem constants (reference: B=16, H=W=1024, WIDTH=3, SIGMA=1, BLUR_SIGMA=1.5, EPS=1e-8)
#define BB    16
#define HH    1024
#define WW    1024
#define NPIX  (HH * WW)          // 1<<20
#define EPSF  1e-8f
#define RAD   4                  // int(3 * 1.5)

struct BlurK { float k[9]; };

__device__ __forceinline__ float sigf(float z) {
    z = fmaxf(fminf(z, 40.f), -40.f);
    return 1.f / (1.f + __expf(-z));
}

struct Geom { float p0x, p0y, p1x, p1y, L, ux, uy; };

__device__ __forceinline__ Geom load_geom(const float* as, const float* ae, int b) {
    Geom g;
    g.p0x = as[3 * b];  g.p0y = as[3 * b + 1];
    g.p1x = ae[3 * b];  g.p1y = ae[3 * b + 1];
    float dx = g.p1x - g.p0x, dy = g.p1y - g.p0y;
    g.L  = sqrtf(dx * dx + dy * dy + EPSF);
    g.ux = dx / g.L;  g.uy = dy / g.L;
    return g;
}

// swept(x,y) = sigmoid(3 - dist to segment p0->p1)
__device__ __forceinline__ float sweptf(const Geom& g, float x, float y) {
    float rx = x - g.p0x, ry = y - g.p0y;
    float t  = fminf(fmaxf(rx * g.ux + ry * g.uy, 0.f), g.L);
    float dx = rx - t * g.ux, dy = ry - t * g.uy;
    float dist = sqrtf(dx * dx + dy * dy + EPSF);
    return sigf(3.f - dist);
}

// s (along-axis from p1) and lat (lateral window)
__device__ __forceinline__ void slat(const Geom& g, float x, float y, float& s, float& lat) {
    float qx = x - g.p1x, qy = y - g.p1y;
    s = qx * g.ux + qy * g.uy;
    float r = qx * (-g.uy) + qy * g.ux;   // n = (-uy, ux)
    lat = sigf(3.f - fabsf(r));
}

// thread0 returns block sum
__device__ __forceinline__ float block_reduce(float v) {
    #pragma unroll
    for (int off = 32; off > 0; off >>= 1) v += __shfl_down(v, off);
    __shared__ float sm[4];
    int lane = threadIdx.x & 63, wid = threadIdx.x >> 6;
    if (lane == 0) sm[wid] = v;
    __syncthreads();
    float r = 0.f;
    if (threadIdx.x == 0) r = sm[0] + sm[1] + sm[2] + sm[3];
    return r;
}

// ---- K1: m_swept[b] = sum(occ * swept) -> accum[b] -------------------------
__global__ void k_mswept(const float* __restrict__ occ, const float* __restrict__ as,
                         const float* __restrict__ ae, float* __restrict__ accum) {
    const int b = blockIdx.y;
    Geom g = load_geom(as, ae, b);
    const float4* base = (const float4*)(occ + ((size_t)b << 20));
    float sum = 0.f;
    const int stride = gridDim.x * blockDim.x;
    for (int i4 = blockIdx.x * blockDim.x + threadIdx.x; i4 < (NPIX >> 2); i4 += stride) {
        float4 v = base[i4];
        int p = i4 << 2;
        float y  = (float)(p >> 10);
        float x0 = (float)(p & 1023);
        sum += v.x * sweptf(g, x0 + 0.f, y);
        sum += v.y * sweptf(g, x0 + 1.f, y);
        sum += v.z * sweptf(g, x0 + 2.f, y);
        sum += v.w * sweptf(g, x0 + 3.f, y);
    }
    float bs = block_reduce(sum);
    if (threadIdx.x == 0) atomicAdd(&accum[b], bs);
}

// ---- K2: existing[b] = sum(occ * probe) -> accum[BB + b] -------------------
__global__ void k_existing(const float* __restrict__ occ, const float* __restrict__ as,
                           const float* __restrict__ ae, float* __restrict__ accum) {
    const int b = blockIdx.y;
    Geom g = load_geom(as, ae, b);
    const float pile = accum[b] * (1.f / 6.f);
    const float4* base = (const float4*)(occ + ((size_t)b << 20));
    float sum = 0.f;
    const int stride = gridDim.x * blockDim.x;
    for (int i4 = blockIdx.x * blockDim.x + threadIdx.x; i4 < (NPIX >> 2); i4 += stride) {
        float4 v = base[i4];
        int p = i4 << 2;
        float y  = (float)(p >> 10);
        float x0 = (float)(p & 1023);
        #pragma unroll
        for (int c = 0; c < 4; c++) {
            float x = x0 + (float)c;
            float s, lat; slat(g, x, y, s, lat);
            float probe = sigf(s) * sigf(pile - s) * lat;
            float occv = (c == 0) ? v.x : (c == 1) ? v.y : (c == 2) ? v.z : v.w;
            sum += occv * probe;
        }
    }
    float bs = block_reduce(sum);
    if (threadIdx.x == 0) atomicAdd(&accum[BB + b], bs);
}

// ---- K3: sum_mask[b] = sum(dep_mask) -> accum[2*BB + b]  (no HBM reads) ----
__global__ void k_summask(const float* __restrict__ as, const float* __restrict__ ae,
                          float* __restrict__ accum) {
    const int b = blockIdx.y;
    Geom g = load_geom(as, ae, b);
    const float pile  = accum[b] * (1.f / 6.f);
    const float extra = accum[BB + b] * (1.f / 6.f);
    float sum = 0.f;
    const int stride = gridDim.x * blockDim.x;
    for (int p = blockIdx.x * blockDim.x + threadIdx.x; p < NPIX; p += stride) {
        float y = (float)(p >> 10);
        float x = (float)(p & 1023);
        float s, lat; slat(g, x, y, s, lat);
        sum += sigf(s - extra) * sigf(extra + pile - s) * lat;
    }
    float bs = block_reduce(sum);
    if (threadIdx.x == 0) atomicAdd(&accum[2 * BB + b], bs);
}

// ---- K4: dep + horizontal blur -> tmp --------------------------------------
__global__ void k_dep_hblur(const float* __restrict__ as, const float* __restrict__ ae,
                            const float* __restrict__ accum, float* __restrict__ tmp,
                            BlurK wk) {
    const int b = blockIdx.z, h = blockIdx.y, wbase = blockIdx.x << 8;
    Geom g = load_geom(as, ae, b);
    const float pile     = accum[b] * (1.f / 6.f);
    const float extra    = accum[BB + b] * (1.f / 6.f);
    const float dep_norm = accum[b] / (accum[2 * BB + b] + EPSF);
    __shared__ float sd[256 + 2 * RAD];
    const float y = (float)h;
    for (int i = threadIdx.x; i < 256 + 2 * RAD; i += 256) {
        int w = wbase - RAD + i;
        float v = 0.f;
        if (w >= 0 && w < WW) {
            float s, lat; slat(g, (float)w, y, s, lat);
            v = sigf(s - extra) * sigf(extra + pile - s) * lat * dep_norm;
        }
        sd[i] = v;
    }
    __syncthreads();
    float acc = 0.f;
    #pragma unroll
    for (int j = 0; j < 9; j++) acc += wk.k[j] * sd[threadIdx.x + j];
    tmp[((size_t)b << 20) + ((size_t)h << 10) + wbase + threadIdx.x] = acc;
}

// ---- K5: vertical blur + combine -> out ------------------------------------
__global__ void k_vblur_combine(const float* __restrict__ occ, const float* __restrict__ as,
                                const float* __restrict__ ae, const float* __restrict__ tmp,
                                float* __restrict__ out, BlurK wk) {
    const int b = blockIdx.z, h = blockIdx.y, tid = threadIdx.x;
    Geom g = load_geom(as, ae, b);
    const size_t rowoff = ((size_t)b << 20) + ((size_t)h << 10);
    float4 o = ((const float4*)(occ + rowoff))[tid];
    float4 acc = make_float4(0.f, 0.f, 0.f, 0.f);
    #pragma unroll
    for (int j = 0; j < 9; j++) {
        int hh = h + j - RAD;
        if (hh >= 0 && hh < HH) {
            float4 v = ((const float4*)(tmp + ((size_t)b << 20) + ((size_t)hh << 10)))[tid];
            float kk = wk.k[j];
            acc.x += kk * v.x; acc.y += kk * v.y; acc.z += kk * v.z; acc.w += kk * v.w;
        }
    }
    const float y = (float)h;
    const float x0 = (float)(tid << 2);
    float4 r;
    r.x = o.x * (1.f - sweptf(g, x0 + 0.f, y)) + acc.x;
    r.y = o.y * (1.f - sweptf(g, x0 + 1.f, y)) + acc.y;
    r.z = o.z * (1.f - sweptf(g, x0 + 2.f, y)) + acc.z;
    r.w = o.w * (1.f - sweptf(g, x0 + 3.f, y)) + acc.w;
    ((float4*)(out + rowoff))[tid] = r;
}

extern "C" void kernel_launch(void* const* d_in, const int* in_sizes, int n_in,
                              void* d_out, int out_size, void* d_ws, size_t ws_size,
                              hipStream_t stream) {
    const float* occ = (const float*)d_in[0];
    const float* as  = (const float*)d_in[1];
    const float* ae  = (const float*)d_in[2];
    float* out   = (float*)d_out;
    float* accum = (float*)d_ws;            // [0..16) m_swept, [16..32) existing, [32..48) sum_mask
    float* tmp   = (float*)d_ws + 64;       // 256-byte offset; needs 64 MiB (ws_size assumed >= 64 MiB + 256 B)

    BlurK wk;
    {
        float s = 0.f;
        for (int i = 0; i < 9; i++) {
            float t = (float)(i - RAD) / 1.5f;
            wk.k[i] = expf(-0.5f * t * t);
            s += wk.k[i];
        }
        for (int i = 0; i < 9; i++) wk.k[i] /= s;
    }

    hipMemsetAsync(d_ws, 0, 64 * sizeof(float), stream);
    k_mswept       <<<dim3(128, BB),       256, 0, stream>>>(occ, as, ae, accum);
    k_existing     <<<dim3(128, BB),       256, 0, stream>>>(occ, as, ae, accum);
    k_summask      <<<dim3(64, BB),        256, 0, stream>>>(as, ae, accum);
    k_dep_hblur    <<<dim3(4, HH, BB),     256, 0, stream>>>(as, ae, accum, tmp, wk);
    k_vblur_combine<<<dim3(1, HH, BB),     256, 0, stream>>>(occ, as, ae, tmp, out, wk);
}

// Round 2
// 200.715 us; speedup vs baseline: 1.7838x; 1.7838x over previous
//
#include <hip/hip_runtime.h>
#include <hip/hip_bf16.h>
#include <math.h>

// Problem constants (reference: B=16, H=W=1024, WIDTH=3, SIGMA=1, BLUR_SIGMA=1.5, EPS=1e-8)
#define BB    16
#define HH    1024
#define WW    1024
#define NPIX  (HH * WW)          // 1<<20
#define EPSF  1e-8f
#define RAD   4                  // blur radius: int(3 * 1.5)
#define MARG  32.f               // support margin: sigmoid tail < e^-29 outside

struct BlurK { float k[9]; };

__device__ __forceinline__ float sigf(float z) {
    z = fmaxf(fminf(z, 40.f), -40.f);
    return 1.f / (1.f + __expf(-z));
}

struct Geom { float p0x, p0y, p1x, p1y, L, ux, uy; };

__device__ __forceinline__ Geom load_geom(const float* as, const float* ae, int b) {
    Geom g;
    g.p0x = as[3 * b];  g.p0y = as[3 * b + 1];
    g.p1x = ae[3 * b];  g.p1y = ae[3 * b + 1];
    float dx = g.p1x - g.p0x, dy = g.p1y - g.p0y;
    g.L  = sqrtf(dx * dx + dy * dy + EPSF);
    g.ux = dx / g.L;  g.uy = dy / g.L;
    return g;
}

__device__ __forceinline__ float sweptf(const Geom& g, float x, float y) {
    float rx = x - g.p0x, ry = y - g.p0y;
    float t  = fminf(fmaxf(rx * g.ux + ry * g.uy, 0.f), g.L);
    float dx = rx - t * g.ux, dy = ry - t * g.uy;
    float dist = sqrtf(dx * dx + dy * dy + EPSF);
    return sigf(3.f - dist);
}

__device__ __forceinline__ void slat(const Geom& g, float x, float y, float& s, float& lat) {
    float qx = x - g.p1x, qy = y - g.p1y;
    s = qx * g.ux + qy * g.uy;
    float r = qx * (-g.uy) + qy * g.ux;   // n = (-uy, ux)
    lat = sigf(3.f - fabsf(r));
}

// bbox of capsule around segment p0->p1 expanded by m, clamped to image
__device__ __forceinline__ void capsule_bbox(const Geom& g, float m,
                                             int& x0, int& x1, int& y0, int& y1) {
    x0 = max(0, (int)floorf(fminf(g.p0x, g.p1x) - m));
    x1 = min(WW - 1, (int)ceilf(fmaxf(g.p0x, g.p1x) + m));
    y0 = max(0, (int)floorf(fminf(g.p0y, g.p1y) - m));
    y1 = min(HH - 1, (int)ceilf(fmaxf(g.p0y, g.p1y) + m));
}

// bbox of rotated strip: s in [s0,s1], r in [-m,m], anchored at p1 along (u,n)
__device__ __forceinline__ void strip_bbox(const Geom& g, float s0, float s1, float m,
                                           int& x0, int& x1, int& y0, int& y1) {
    float xmin = 1e9f, xmax = -1e9f, ymin = 1e9f, ymax = -1e9f;
    #pragma unroll
    for (int i = 0; i < 4; i++) {
        float s = (i & 1) ? s1 : s0;
        float r = (i & 2) ? m : -m;
        float x = g.p1x + s * g.ux - r * g.uy;
        float y = g.p1y + s * g.uy + r * g.ux;
        xmin = fminf(xmin, x); xmax = fmaxf(xmax, x);
        ymin = fminf(ymin, y); ymax = fmaxf(ymax, y);
    }
    x0 = max(0, (int)floorf(xmin)); x1 = min(WW - 1, (int)ceilf(xmax));
    y0 = max(0, (int)floorf(ymin)); y1 = min(HH - 1, (int)ceilf(ymax));
}

// thread0 returns block sum (blockDim.x == 256)
__device__ __forceinline__ float block_reduce(float v) {
    #pragma unroll
    for (int off = 32; off > 0; off >>= 1) v += __shfl_down(v, off);
    __shared__ float sm[4];
    int lane = threadIdx.x & 63, wid = threadIdx.x >> 6;
    if (lane == 0) sm[wid] = v;
    __syncthreads();
    float r = 0.f;
    if (threadIdx.x == 0) r = sm[0] + sm[1] + sm[2] + sm[3];
    return r;
}

// ---- K1: full-image copy out<-occ, fused m_swept reduction over capsule bbox
__global__ void k_copy_mswept(const float* __restrict__ occ, const float* __restrict__ as,
                              const float* __restrict__ ae, float* __restrict__ out,
                              float* __restrict__ accum) {
    const int b = blockIdx.y;
    Geom g = load_geom(as, ae, b);
    int cx0, cx1, cy0, cy1; capsule_bbox(g, MARG, cx0, cx1, cy0, cy1);
    const float4* src = (const float4*)(occ + ((size_t)b << 20));
    float4* dst = (float4*)(out + ((size_t)b << 20));
    float sum = 0.f;
    const int stride = gridDim.x * blockDim.x;
    for (int i4 = blockIdx.x * blockDim.x + threadIdx.x; i4 < (NPIX >> 2); i4 += stride) {
        float4 v = src[i4];
        dst[i4] = v;
        int p = i4 << 2;
        int y = p >> 10, x = p & 1023;
        if (y >= cy0 && y <= cy1 && x + 3 >= cx0 && x <= cx1) {
            float fy = (float)y, fx = (float)x;
            sum += v.x * sweptf(g, fx + 0.f, fy);
            sum += v.y * sweptf(g, fx + 1.f, fy);
            sum += v.z * sweptf(g, fx + 2.f, fy);
            sum += v.w * sweptf(g, fx + 3.f, fy);
        }
    }
    float bs = block_reduce(sum);
    if (threadIdx.x == 0) atomicAdd(&accum[b], bs);
}

// ---- K2: existing[b] = sum(occ * probe) over probe-strip bbox --------------
__global__ void k_existing(const float* __restrict__ occ, const float* __restrict__ as,
                           const float* __restrict__ ae, float* __restrict__ accum) {
    const int b = blockIdx.y;
    Geom g = load_geom(as, ae, b);
    const float pile = accum[b] * (1.f / 6.f);
    int x0, x1, y0, y1; strip_bbox(g, -MARG, pile + MARG, MARG, x0, x1, y0, y1);
    const float* base = occ + ((size_t)b << 20);
    float sum = 0.f;
    for (int row = y0 + blockIdx.x; row <= y1; row += gridDim.x) {
        float fy = (float)row;
        for (int x = x0 + threadIdx.x; x <= x1; x += 256) {
            float s, lat; slat(g, (float)x, fy, s, lat);
            float probe = sigf(s) * sigf(pile - s) * lat;
            sum += base[((size_t)row << 10) + x] * probe;
        }
    }
    float bs = block_reduce(sum);
    if (threadIdx.x == 0) atomicAdd(&accum[BB + b], bs);
}

// ---- K3: summask[b] = sum(dep_mask) over dep-strip bbox (no HBM reads) -----
__global__ void k_summask(const float* __restrict__ as, const float* __restrict__ ae,
                          float* __restrict__ accum) {
    const int b = blockIdx.y;
    Geom g = load_geom(as, ae, b);
    const float pile  = accum[b] * (1.f / 6.f);
    const float extra = accum[BB + b] * (1.f / 6.f);
    int x0, x1, y0, y1; strip_bbox(g, extra - MARG, extra + pile + MARG, MARG, x0, x1, y0, y1);
    float sum = 0.f;
    for (int row = y0 + blockIdx.x; row <= y1; row += gridDim.x) {
        float fy = (float)row;
        for (int x = x0 + threadIdx.x; x <= x1; x += 256) {
            float s, lat; slat(g, (float)x, fy, s, lat);
            sum += sigf(s - extra) * sigf(extra + pile - s) * lat;
        }
    }
    float bs = block_reduce(sum);
    if (threadIdx.x == 0) atomicAdd(&accum[2 * BB + b], bs);
}

// ---- K4: patch union bbox: out = occ*(1-swept) + blur(dep), LDS-local blur -
#define TH 8
#define TW 128
__global__ void k_patch(const float* __restrict__ occ, const float* __restrict__ as,
                        const float* __restrict__ ae, const float* __restrict__ accum,
                        float* __restrict__ out, BlurK wk) {
    const int b = blockIdx.y;
    Geom g = load_geom(as, ae, b);
    const float pile     = accum[b] * (1.f / 6.f);
    const float extra    = accum[BB + b] * (1.f / 6.f);
    const float dep_norm = accum[b] / (accum[2 * BB + b] + EPSF);

    // union bbox = capsule bbox U dep strip bbox (blur radius covered by MARG)
    int cx0, cx1, cy0, cy1; capsule_bbox(g, MARG, cx0, cx1, cy0, cy1);
    int sx0, sx1, sy0, sy1; strip_bbox(g, extra - MARG, extra + pile + MARG, MARG, sx0, sx1, sy0, sy1);
    const int ux0 = min(cx0, sx0), ux1 = max(cx1, sx1);
    const int uy0 = min(cy0, sy0), uy1 = max(cy1, sy1);
    const int bw = ux1 - ux0 + 1, bh = uy1 - uy0 + 1;
    const int ntx = (bw + TW - 1) / TW, nty = (bh + TH - 1) / TH;

    __shared__ float draw[TH + 2 * RAD][TW + 2 * RAD];
    __shared__ float hb[TH + 2 * RAD][TW];
    const float* ob = occ + ((size_t)b << 20);
    float* outb = out + ((size_t)b << 20);
    const int tid = threadIdx.x;

    for (int t = blockIdx.x; t < ntx * nty; t += gridDim.x) {
        const int tx = t % ntx, ty = t / ntx;
        const int xt = ux0 + tx * TW, yt = uy0 + ty * TH;
        // dep with 4-px halo
        for (int i = tid; i < (TH + 8) * (TW + 8); i += 256) {
            int ly = i / (TW + 8), lx = i % (TW + 8);
            int gy = yt - RAD + ly, gx = xt - RAD + lx;
            float v = 0.f;
            if (gx >= 0 && gx < WW && gy >= 0 && gy < HH) {
                float s, lat; slat(g, (float)gx, (float)gy, s, lat);
                v = sigf(s - extra) * sigf(extra + pile - s) * lat * dep_norm;
            }
            draw[ly][lx] = v;
        }
        __syncthreads();
        // horizontal blur
        for (int i = tid; i < (TH + 8) * TW; i += 256) {
            int ly = i / TW, lx = i % TW;
            float acc = 0.f;
            #pragma unroll
            for (int j = 0; j < 9; j++) acc += wk.k[j] * draw[ly][lx + j];
            hb[ly][lx] = acc;
        }
        __syncthreads();
        // vertical blur + combine + store
        for (int i = tid; i < TH * TW; i += 256) {
            int ly = i / TW, lx = i % TW;
            int gy = yt + ly, gx = xt + lx;
            if (gy < HH && gx < WW) {
                float acc = 0.f;
                #pragma unroll
                for (int j = 0; j < 9; j++) acc += wk.k[j] * hb[ly + j][lx];
                size_t off = ((size_t)gy << 10) + gx;
                float o = ob[off];
                outb[off] = o * (1.f - sweptf(g, (float)gx, (float)gy)) + acc;
            }
        }
        __syncthreads();
    }
}

extern "C" void kernel_launch(void* const* d_in, const int* in_sizes, int n_in,
                              void* d_out, int out_size, void* d_ws, size_t ws_size,
                              hipStream_t stream) {
    const float* occ = (const float*)d_in[0];
    const float* as  = (const float*)d_in[1];
    const float* ae  = (const float*)d_in[2];
    float* out   = (float*)d_out;
    float* accum = (float*)d_ws;   // [0..16) m_swept, [16..32) existing, [32..48) summask

    BlurK wk;
    {
        float s = 0.f;
        for (int i = 0; i < 9; i++) {
            float t = (float)(i - RAD) / 1.5f;
            wk.k[i] = expf(-0.5f * t * t);
            s += wk.k[i];
        }
        for (int i = 0; i < 9; i++) wk.k[i] /= s;
    }

    hipMemsetAsync(d_ws, 0, 64 * sizeof(float), stream);
    k_copy_mswept<<<dim3(256, BB), 256, 0, stream>>>(occ, as, ae, out, accum);
    k_existing   <<<dim3(64,  BB), 256, 0, stream>>>(occ, as, ae, accum);
    k_summask    <<<dim3(64,  BB), 256, 0, stream>>>(as, ae, accum);
    k_patch      <<<dim3(128, BB), 256, 0, stream>>>(occ, as, ae, accum, out, wk);
}

// Round 3
// 171.732 us; speedup vs baseline: 2.0849x; 1.1688x over previous
//
#include <hip/hip_runtime.h>
#include <hip/hip_bf16.h>
#include <math.h>

// Problem constants (reference: B=16, H=W=1024, WIDTH=3, SIGMA=1, BLUR_SIGMA=1.5, EPS=1e-8)
#define BB    16
#define HH    1024
#define WW    1024
#define NPIX  (HH * WW)          // 1<<20
#define EPSF  1e-8f
#define RAD   4                  // blur radius: int(3 * 1.5)
#define MARG  24.f               // support margin: sigmoid tail sigma(3-24) ~ 7.6e-10

struct BlurK { float k[9]; };

__device__ __forceinline__ float sigf(float z) {
    z = fmaxf(fminf(z, 40.f), -40.f);
    return 1.f / (1.f + __expf(-z));
}

struct Geom { float p0x, p0y, p1x, p1y, L, ux, uy; };

__device__ __forceinline__ Geom load_geom(const float* as, const float* ae, int b) {
    Geom g;
    g.p0x = as[3 * b];  g.p0y = as[3 * b + 1];
    g.p1x = ae[3 * b];  g.p1y = ae[3 * b + 1];
    float dx = g.p1x - g.p0x, dy = g.p1y - g.p0y;
    g.L  = sqrtf(dx * dx + dy * dy + EPSF);
    g.ux = dx / g.L;  g.uy = dy / g.L;
    return g;
}

__device__ __forceinline__ float sweptf(const Geom& g, float x, float y) {
    float rx = x - g.p0x, ry = y - g.p0y;
    float t  = fminf(fmaxf(rx * g.ux + ry * g.uy, 0.f), g.L);
    float dx = rx - t * g.ux, dy = ry - t * g.uy;
    float dist = sqrtf(dx * dx + dy * dy + EPSF);
    return sigf(3.f - dist);
}

__device__ __forceinline__ void slat(const Geom& g, float x, float y, float& s, float& lat) {
    float qx = x - g.p1x, qy = y - g.p1y;
    s = qx * g.ux + qy * g.uy;
    float r = qx * (-g.uy) + qy * g.ux;   // n = (-uy, ux)
    lat = sigf(3.f - fabsf(r));
}

// bbox of capsule around segment p0->p1 expanded by m, clamped to image
__device__ __forceinline__ void capsule_bbox(const Geom& g, float m,
                                             int& x0, int& x1, int& y0, int& y1) {
    x0 = max(0, (int)floorf(fminf(g.p0x, g.p1x) - m));
    x1 = min(WW - 1, (int)ceilf(fmaxf(g.p0x, g.p1x) + m));
    y0 = max(0, (int)floorf(fminf(g.p0y, g.p1y) - m));
    y1 = min(HH - 1, (int)ceilf(fmaxf(g.p0y, g.p1y) + m));
}

// bbox of rotated strip: s in [s0,s1], r in [-m,m], anchored at p1 along (u,n)
__device__ __forceinline__ void strip_bbox(const Geom& g, float s0, float s1, float m,
                                           int& x0, int& x1, int& y0, int& y1) {
    float xmin = 1e9f, xmax = -1e9f, ymin = 1e9f, ymax = -1e9f;
    #pragma unroll
    for (int i = 0; i < 4; i++) {
        float s = (i & 1) ? s1 : s0;
        float r = (i & 2) ? m : -m;
        float x = g.p1x + s * g.ux - r * g.uy;
        float y = g.p1y + s * g.uy + r * g.ux;
        xmin = fminf(xmin, x); xmax = fmaxf(xmax, x);
        ymin = fminf(ymin, y); ymax = fmaxf(ymax, y);
    }
    x0 = max(0, (int)floorf(xmin)); x1 = min(WW - 1, (int)ceilf(xmax));
    y0 = max(0, (int)floorf(ymin)); y1 = min(HH - 1, (int)ceilf(ymax));
}

// ---- K1: all three reductions, one 1024-thread block per image -------------
// accum[b] = m_swept, accum[16+b] = existing, accum[32+b] = summask
__device__ __forceinline__ float block_reduce_bcast_1024(float v, float* sm) {
    const int tid = threadIdx.x, lane = tid & 63, wid = tid >> 6;
    #pragma unroll
    for (int off = 32; off > 0; off >>= 1) v += __shfl_down(v, off);
    if (lane == 0) sm[wid] = v;
    __syncthreads();
    if (tid == 0) {
        float r = 0.f;
        #pragma unroll
        for (int i = 0; i < 16; i++) r += sm[i];
        sm[16] = r;
    }
    __syncthreads();
    float r = sm[16];
    __syncthreads();   // safe reuse of sm in the next phase
    return r;
}

__global__ __launch_bounds__(1024)
void k_reduce(const float* __restrict__ occ, const float* __restrict__ as,
              const float* __restrict__ ae, float* __restrict__ accum) {
    const int b = blockIdx.x, tid = threadIdx.x;
    Geom g = load_geom(as, ae, b);
    const float* base = occ + ((size_t)b << 20);
    __shared__ float sm[17];

    // phase 1: m_swept over capsule bbox
    int x0, x1, y0, y1; capsule_bbox(g, MARG, x0, x1, y0, y1);
    int w = x1 - x0 + 1, n = w * (y1 - y0 + 1);
    float sum = 0.f;
    for (int i = tid; i < n; i += 1024) {
        int y = y0 + i / w, x = x0 + i % w;
        sum += base[((size_t)y << 10) + x] * sweptf(g, (float)x, (float)y);
    }
    float m_swept = block_reduce_bcast_1024(sum, sm);
    const float pile = m_swept * (1.f / 6.f);

    // phase 2: existing over probe strip bbox
    strip_bbox(g, -MARG, pile + MARG, MARG, x0, x1, y0, y1);
    w = x1 - x0 + 1; n = w * (y1 - y0 + 1);
    sum = 0.f;
    for (int i = tid; i < n; i += 1024) {
        int y = y0 + i / w, x = x0 + i % w;
        float s, lat; slat(g, (float)x, (float)y, s, lat);
        sum += base[((size_t)y << 10) + x] * sigf(s) * sigf(pile - s) * lat;
    }
    float existing = block_reduce_bcast_1024(sum, sm);
    const float extra = existing * (1.f / 6.f);

    // phase 3: summask over dep strip bbox (no loads)
    strip_bbox(g, extra - MARG, extra + pile + MARG, MARG, x0, x1, y0, y1);
    w = x1 - x0 + 1; n = w * (y1 - y0 + 1);
    sum = 0.f;
    for (int i = tid; i < n; i += 1024) {
        int y = y0 + i / w, x = x0 + i % w;
        float s, lat; slat(g, (float)x, (float)y, s, lat);
        sum += sigf(s - extra) * sigf(extra + pile - s) * lat;
    }
    float summask = block_reduce_bcast_1024(sum, sm);

    if (tid == 0) {
        accum[b]          = m_swept;
        accum[BB + b]     = existing;
        accum[2 * BB + b] = summask;
    }
}

// ---- K2: pure full-image copy, 8 outstanding float4 per thread -------------
// total float4 = BB<<18 = 4,194,304; block covers 2048; grid = 2048 exact
__global__ __launch_bounds__(256)
void k_copy(const float4* __restrict__ src, float4* __restrict__ dst) {
    const size_t base = (size_t)blockIdx.x * 2048 + threadIdx.x;
    float4 v[8];
    #pragma unroll
    for (int k = 0; k < 8; k++) v[k] = src[base + (size_t)k * 256];
    #pragma unroll
    for (int k = 0; k < 8; k++) dst[base + (size_t)k * 256] = v[k];
}

// ---- K3: patch union bbox: out = occ*(1-swept) + blur(dep), LDS-local blur -
#define TH 8
#define TW 128
__global__ void k_patch(const float* __restrict__ occ, const float* __restrict__ as,
                        const float* __restrict__ ae, const float* __restrict__ accum,
                        float* __restrict__ out, BlurK wk) {
    const int b = blockIdx.y;
    Geom g = load_geom(as, ae, b);
    const float pile     = accum[b] * (1.f / 6.f);
    const float extra    = accum[BB + b] * (1.f / 6.f);
    const float dep_norm = accum[b] / (accum[2 * BB + b] + EPSF);

    int cx0, cx1, cy0, cy1; capsule_bbox(g, MARG, cx0, cx1, cy0, cy1);
    int sx0, sx1, sy0, sy1; strip_bbox(g, extra - MARG, extra + pile + MARG, MARG, sx0, sx1, sy0, sy1);
    const int ux0 = min(cx0, sx0), ux1 = max(cx1, sx1);
    const int uy0 = min(cy0, sy0), uy1 = max(cy1, sy1);
    const int bw = ux1 - ux0 + 1, bh = uy1 - uy0 + 1;
    const int ntx = (bw + TW - 1) / TW, nty = (bh + TH - 1) / TH;

    __shared__ float draw[TH + 2 * RAD][TW + 2 * RAD];
    __shared__ float hb[TH + 2 * RAD][TW];
    const float* ob = occ + ((size_t)b << 20);
    float* outb = out + ((size_t)b << 20);
    const int tid = threadIdx.x;

    for (int t = blockIdx.x; t < ntx * nty; t += gridDim.x) {
        const int tx = t % ntx, ty = t / ntx;
        const int xt = ux0 + tx * TW, yt = uy0 + ty * TH;
        // dep with 4-px halo
        for (int i = tid; i < (TH + 8) * (TW + 8); i += 256) {
            int ly = i / (TW + 8), lx = i % (TW + 8);
            int gy = yt - RAD + ly, gx = xt - RAD + lx;
            float v = 0.f;
            if (gx >= 0 && gx < WW && gy >= 0 && gy < HH) {
                float s, lat; slat(g, (float)gx, (float)gy, s, lat);
                v = sigf(s - extra) * sigf(extra + pile - s) * lat * dep_norm;
            }
            draw[ly][lx] = v;
        }
        __syncthreads();
        // horizontal blur
        for (int i = tid; i < (TH + 8) * TW; i += 256) {
            int ly = i / TW, lx = i % TW;
            float acc = 0.f;
            #pragma unroll
            for (int j = 0; j < 9; j++) acc += wk.k[j] * draw[ly][lx + j];
            hb[ly][lx] = acc;
        }
        __syncthreads();
        // vertical blur + combine + store
        for (int i = tid; i < TH * TW; i += 256) {
            int ly = i / TW, lx = i % TW;
            int gy = yt + ly, gx = xt + lx;
            if (gy < HH && gx < WW) {
                float acc = 0.f;
                #pragma unroll
                for (int j = 0; j < 9; j++) acc += wk.k[j] * hb[ly + j][lx];
                size_t off = ((size_t)gy << 10) + gx;
                float o = ob[off];
                outb[off] = o * (1.f - sweptf(g, (float)gx, (float)gy)) + acc;
            }
        }
        __syncthreads();
    }
}

extern "C" void kernel_launch(void* const* d_in, const int* in_sizes, int n_in,
                              void* d_out, int out_size, void* d_ws, size_t ws_size,
                              hipStream_t stream) {
    const float* occ = (const float*)d_in[0];
    const float* as  = (const float*)d_in[1];
    const float* ae  = (const float*)d_in[2];
    float* out   = (float*)d_out;
    float* accum = (float*)d_ws;   // [0..16) m_swept, [16..32) existing, [32..48) summask

    BlurK wk;
    {
        float s = 0.f;
        for (int i = 0; i < 9; i++) {
            float t = (float)(i - RAD) / 1.5f;
            wk.k[i] = expf(-0.5f * t * t);
            s += wk.k[i];
        }
        for (int i = 0; i < 9; i++) wk.k[i] /= s;
    }

    k_reduce<<<dim3(BB),      1024, 0, stream>>>(occ, as, ae, accum);
    k_copy  <<<dim3(2048),     256, 0, stream>>>((const float4*)occ, (float4*)out);
    k_patch <<<dim3(128, BB),  256, 0, stream>>>(occ, as, ae, accum, out, wk);
}

// Round 4
// 165.442 us; speedup vs baseline: 2.1642x; 1.0380x over previous
//
#include <hip/hip_runtime.h>
#include <hip/hip_bf16.h>
#include <math.h>

// Problem constants (reference: B=16, H=W=1024, WIDTH=3, SIGMA=1, BLUR_SIGMA=1.5, EPS=1e-8)
#define BB    16
#define HH    1024
#define WW    1024
#define NPIX  (HH * WW)          // 1<<20
#define EPSF  1e-8f
#define RAD   4                  // blur radius: int(3 * 1.5)
#define MARG  24.f               // support margin: sigma(3-24) ~ 7.6e-10
#define NBX   128                // blocks per image in phase kernels
#define NPATCH 64                // blocks per image in final kernel

struct BlurK { float k[9]; };

__device__ __forceinline__ float sigf(float z) {
    z = fmaxf(fminf(z, 40.f), -40.f);
    return 1.f / (1.f + __expf(-z));
}

struct Geom { float p0x, p0y, p1x, p1y, L, ux, uy; };

__device__ __forceinline__ Geom load_geom(const float* as, const float* ae, int b) {
    Geom g;
    g.p0x = as[3 * b];  g.p0y = as[3 * b + 1];
    g.p1x = ae[3 * b];  g.p1y = ae[3 * b + 1];
    float dx = g.p1x - g.p0x, dy = g.p1y - g.p0y;
    g.L  = sqrtf(dx * dx + dy * dy + EPSF);
    g.ux = dx / g.L;  g.uy = dy / g.L;
    return g;
}

__device__ __forceinline__ float sweptf(const Geom& g, float x, float y) {
    float rx = x - g.p0x, ry = y - g.p0y;
    float t  = fminf(fmaxf(rx * g.ux + ry * g.uy, 0.f), g.L);
    float dx = rx - t * g.ux, dy = ry - t * g.uy;
    float dist = sqrtf(dx * dx + dy * dy + EPSF);
    return sigf(3.f - dist);
}

__device__ __forceinline__ void slat(const Geom& g, float x, float y, float& s, float& lat) {
    float qx = x - g.p1x, qy = y - g.p1y;
    s = qx * g.ux + qy * g.uy;
    float r = qx * (-g.uy) + qy * g.ux;   // n = (-uy, ux)
    lat = sigf(3.f - fabsf(r));
}

__device__ __forceinline__ void capsule_bbox(const Geom& g, float m,
                                             int& x0, int& x1, int& y0, int& y1) {
    x0 = max(0, (int)floorf(fminf(g.p0x, g.p1x) - m));
    x1 = min(WW - 1, (int)ceilf(fmaxf(g.p0x, g.p1x) + m));
    y0 = max(0, (int)floorf(fminf(g.p0y, g.p1y) - m));
    y1 = min(HH - 1, (int)ceilf(fmaxf(g.p0y, g.p1y) + m));
}

__device__ __forceinline__ void strip_bbox(const Geom& g, float s0, float s1, float m,
                                           int& x0, int& x1, int& y0, int& y1) {
    float xmin = 1e9f, xmax = -1e9f, ymin = 1e9f, ymax = -1e9f;
    #pragma unroll
    for (int i = 0; i < 4; i++) {
        float s = (i & 1) ? s1 : s0;
        float r = (i & 2) ? m : -m;
        float x = g.p1x + s * g.ux - r * g.uy;
        float y = g.p1y + s * g.uy + r * g.ux;
        xmin = fminf(xmin, x); xmax = fmaxf(xmax, x);
        ymin = fminf(ymin, y); ymax = fmaxf(ymax, y);
    }
    x0 = max(0, (int)floorf(xmin)); x1 = min(WW - 1, (int)ceilf(xmax));
    y0 = max(0, (int)floorf(ymin)); y1 = min(HH - 1, (int)ceilf(ymax));
}

// 256-thread block reduce, result broadcast to all threads; sm is float[4]
__device__ __forceinline__ float brb256(float v, float* sm) {
    #pragma unroll
    for (int off = 32; off > 0; off >>= 1) v += __shfl_down(v, off);
    const int lane = threadIdx.x & 63, wid = threadIdx.x >> 6;
    if (lane == 0) sm[wid] = v;
    __syncthreads();
    float r = sm[0] + sm[1] + sm[2] + sm[3];
    __syncthreads();
    return r;
}

// ---- K1: copy first half of each image + m_swept partials ------------------
__global__ __launch_bounds__(256)
void k_phase1(const float* __restrict__ occ, const float* __restrict__ as,
              const float* __restrict__ ae, float* __restrict__ out,
              float* __restrict__ part1) {
    const int b = blockIdx.y, bx = blockIdx.x, tid = threadIdx.x;
    const float4* src = (const float4*)(occ + ((size_t)b << 20));
    float4*       dst = (float4*)(out + ((size_t)b << 20));
    const int cb = bx * 1024 + tid;       // 128 blocks x 1024 = 131072 float4 = half image
    float4 v0 = src[cb];
    float4 v1 = src[cb + 256];
    float4 v2 = src[cb + 512];
    float4 v3 = src[cb + 768];

    Geom g = load_geom(as, ae, b);
    int x0, x1, y0, y1; capsule_bbox(g, MARG, x0, x1, y0, y1);
    const float* base = occ + ((size_t)b << 20);
    float sum = 0.f;
    for (int y = y0 + bx; y <= y1; y += NBX) {
        float fy = (float)y;
        for (int x = x0 + tid; x <= x1; x += 256)
            sum += base[((size_t)y << 10) + x] * sweptf(g, (float)x, fy);
    }

    dst[cb] = v0; dst[cb + 256] = v1; dst[cb + 512] = v2; dst[cb + 768] = v3;

    __shared__ float sm[4];
    float bs = brb256(sum, sm);
    if (tid == 0) part1[b * NBX + bx] = bs;
}

// ---- K2: copy second half + existing partials ------------------------------
__global__ __launch_bounds__(256)
void k_phase2(const float* __restrict__ occ, const float* __restrict__ as,
              const float* __restrict__ ae, float* __restrict__ out,
              const float* __restrict__ part1, float* __restrict__ part2) {
    const int b = blockIdx.y, bx = blockIdx.x, tid = threadIdx.x;
    const float4* src = (const float4*)(occ + ((size_t)b << 20));
    float4*       dst = (float4*)(out + ((size_t)b << 20));
    const int cb = 131072 + bx * 1024 + tid;
    float4 v0 = src[cb];
    float4 v1 = src[cb + 256];
    float4 v2 = src[cb + 512];
    float4 v3 = src[cb + 768];

    __shared__ float sm[4];
    float pv = (tid < NBX) ? part1[b * NBX + tid] : 0.f;
    const float m_swept = brb256(pv, sm);
    const float pile = m_swept * (1.f / 6.f);

    Geom g = load_geom(as, ae, b);
    int x0, x1, y0, y1; strip_bbox(g, -MARG, pile + MARG, MARG, x0, x1, y0, y1);
    const float* base = occ + ((size_t)b << 20);
    float sum = 0.f;
    for (int y = y0 + bx; y <= y1; y += NBX) {
        float fy = (float)y;
        for (int x = x0 + tid; x <= x1; x += 256) {
            float s, lat; slat(g, (float)x, fy, s, lat);
            sum += base[((size_t)y << 10) + x] * sigf(s) * sigf(pile - s) * lat;
        }
    }

    dst[cb] = v0; dst[cb + 256] = v1; dst[cb + 512] = v2; dst[cb + 768] = v3;

    float bs = brb256(sum, sm);
    if (tid == 0) part2[b * NBX + bx] = bs;
}

// ---- K3: per-block redundant summask + patch (LDS separable blur) ----------
#define TH 8
#define TW 128
__global__ __launch_bounds__(256)
void k_final(const float* __restrict__ occ, const float* __restrict__ as,
             const float* __restrict__ ae, const float* __restrict__ part1,
             const float* __restrict__ part2, float* __restrict__ out, BlurK wk) {
    const int b = blockIdx.y, bx = blockIdx.x, tid = threadIdx.x;
    __shared__ float sm[4];
    Geom g = load_geom(as, ae, b);

    const float m_swept  = brb256((tid < NBX) ? part1[b * NBX + tid] : 0.f, sm);
    const float existing = brb256((tid < NBX) ? part2[b * NBX + tid] : 0.f, sm);
    const float pile  = m_swept * (1.f / 6.f);
    const float extra = existing * (1.f / 6.f);

    // redundant per-block summask over dep strip bbox (no loads, ~2-4 us)
    int sx0, sx1, sy0, sy1;
    strip_bbox(g, extra - MARG, extra + pile + MARG, MARG, sx0, sx1, sy0, sy1);
    float sum = 0.f;
    {
        const int w = sx1 - sx0 + 1, n = w * (sy1 - sy0 + 1);
        for (int i = tid; i < n; i += 256) {
            int y = sy0 + i / w, x = sx0 + i % w;
            float s, lat; slat(g, (float)x, (float)y, s, lat);
            sum += sigf(s - extra) * sigf(extra + pile - s) * lat;
        }
    }
    const float summask = brb256(sum, sm);
    const float dep_norm = m_swept / (summask + EPSF);

    // union bbox
    int cx0, cx1, cy0, cy1; capsule_bbox(g, MARG, cx0, cx1, cy0, cy1);
    const int ux0 = min(cx0, sx0), ux1 = max(cx1, sx1);
    const int uy0 = min(cy0, sy0), uy1 = max(cy1, sy1);
    const int bw = ux1 - ux0 + 1, bh = uy1 - uy0 + 1;
    const int ntx = (bw + TW - 1) / TW, nty = (bh + TH - 1) / TH;

    __shared__ float draw[TH + 2 * RAD][TW + 2 * RAD];
    __shared__ float hb[TH + 2 * RAD][TW];
    const float* ob = occ + ((size_t)b << 20);
    float* outb = out + ((size_t)b << 20);

    for (int t = bx; t < ntx * nty; t += NPATCH) {
        const int tx = t % ntx, ty = t / ntx;
        const int xt = ux0 + tx * TW, yt = uy0 + ty * TH;
        // dep with 4-px halo
        for (int i = tid; i < (TH + 8) * (TW + 8); i += 256) {
            int ly = i / (TW + 8), lx = i % (TW + 8);
            int gy = yt - RAD + ly, gx = xt - RAD + lx;
            float v = 0.f;
            if (gx >= 0 && gx < WW && gy >= 0 && gy < HH) {
                float s, lat; slat(g, (float)gx, (float)gy, s, lat);
                v = sigf(s - extra) * sigf(extra + pile - s) * lat * dep_norm;
            }
            draw[ly][lx] = v;
        }
        __syncthreads();
        // horizontal blur
        for (int i = tid; i < (TH + 8) * TW; i += 256) {
            int ly = i / TW, lx = i % TW;
            float acc = 0.f;
            #pragma unroll
            for (int j = 0; j < 9; j++) acc += wk.k[j] * draw[ly][lx + j];
            hb[ly][lx] = acc;
        }
        __syncthreads();
        // vertical blur + combine + store
        for (int i = tid; i < TH * TW; i += 256) {
            int ly = i / TW, lx = i % TW;
            int gy = yt + ly, gx = xt + lx;
            if (gy < HH && gx < WW) {
                float acc = 0.f;
                #pragma unroll
                for (int j = 0; j < 9; j++) acc += wk.k[j] * hb[ly + j][lx];
                size_t off = ((size_t)gy << 10) + gx;
                float o = ob[off];
                outb[off] = o * (1.f - sweptf(g, (float)gx, (float)gy)) + acc;
            }
        }
        __syncthreads();
    }
}

extern "C" void kernel_launch(void* const* d_in, const int* in_sizes, int n_in,
                              void* d_out, int out_size, void* d_ws, size_t ws_size,
                              hipStream_t stream) {
    const float* occ = (const float*)d_in[0];
    const float* as  = (const float*)d_in[1];
    const float* ae  = (const float*)d_in[2];
    float* out   = (float*)d_out;
    float* part1 = (float*)d_ws;                 // BB*NBX floats
    float* part2 = (float*)d_ws + BB * NBX;      // BB*NBX floats

    BlurK wk;
    {
        float s = 0.f;
        for (int i = 0; i < 9; i++) {
            float t = (float)(i - RAD) / 1.5f;
            wk.k[i] = expf(-0.5f * t * t);
            s += wk.k[i];
        }
        for (int i = 0; i < 9; i++) wk.k[i] /= s;
    }

    k_phase1<<<dim3(NBX, BB),    256, 0, stream>>>(occ, as, ae, out, part1);
    k_phase2<<<dim3(NBX, BB),    256, 0, stream>>>(occ, as, ae, out, part1, part2);
    k_final <<<dim3(NPATCH, BB), 256, 0, stream>>>(occ, as, ae, part1, part2, out, wk);
}

// Round 5
// 142.814 us; speedup vs baseline: 2.5071x; 1.1584x over previous
//
#include <hip/hip_runtime.h>
#include <hip/hip_bf16.h>
#include <math.h>

// Problem constants (reference: B=16, H=W=1024, WIDTH=3, SIGMA=1, BLUR_SIGMA=1.5, EPS=1e-8)
#define BB    16
#define HH    1024
#define WW    1024
#define NPIX  (HH * WW)          // 1<<20
#define EPSF  1e-8f
#define RAD   4                  // blur radius: int(3 * 1.5)
#define MARG  24.f               // support margin: sigma(3-24) ~ 7.6e-10
#define NB1   128                // blocks per image in copy kernel (8 rows each)
#define NB2   64                 // blocks per image in small kernels

struct BlurK { float k[9]; };

__device__ __forceinline__ float sigf(float z) {
    z = fmaxf(fminf(z, 40.f), -40.f);
    return 1.f / (1.f + __expf(-z));
}

struct Geom { float p0x, p0y, p1x, p1y, L, ux, uy; };

__device__ __forceinline__ Geom load_geom(const float* as, const float* ae, int b) {
    Geom g;
    g.p0x = as[3 * b];  g.p0y = as[3 * b + 1];
    g.p1x = ae[3 * b];  g.p1y = ae[3 * b + 1];
    float dx = g.p1x - g.p0x, dy = g.p1y - g.p0y;
    g.L  = sqrtf(dx * dx + dy * dy + EPSF);
    g.ux = dx / g.L;  g.uy = dy / g.L;
    return g;
}

__device__ __forceinline__ float sweptf(const Geom& g, float x, float y) {
    float rx = x - g.p0x, ry = y - g.p0y;
    float t  = fminf(fmaxf(rx * g.ux + ry * g.uy, 0.f), g.L);
    float dx = rx - t * g.ux, dy = ry - t * g.uy;
    float dist = sqrtf(dx * dx + dy * dy + EPSF);
    return sigf(3.f - dist);
}

__device__ __forceinline__ void slat(const Geom& g, float x, float y, float& s, float& lat) {
    float qx = x - g.p1x, qy = y - g.p1y;
    s = qx * g.ux + qy * g.uy;
    float r = qx * (-g.uy) + qy * g.ux;   // n = (-uy, ux)
    lat = sigf(3.f - fabsf(r));
}

__device__ __forceinline__ void capsule_bbox(const Geom& g, float m,
                                             int& x0, int& x1, int& y0, int& y1) {
    x0 = max(0, (int)floorf(fminf(g.p0x, g.p1x) - m));
    x1 = min(WW - 1, (int)ceilf(fmaxf(g.p0x, g.p1x) + m));
    y0 = max(0, (int)floorf(fminf(g.p0y, g.p1y) - m));
    y1 = min(HH - 1, (int)ceilf(fmaxf(g.p0y, g.p1y) + m));
}

__device__ __forceinline__ void strip_bbox(const Geom& g, float s0, float s1, float m,
                                           int& x0, int& x1, int& y0, int& y1) {
    float xmin = 1e9f, xmax = -1e9f, ymin = 1e9f, ymax = -1e9f;
    #pragma unroll
    for (int i = 0; i < 4; i++) {
        float s = (i & 1) ? s1 : s0;
        float r = (i & 2) ? m : -m;
        float x = g.p1x + s * g.ux - r * g.uy;
        float y = g.p1y + s * g.uy + r * g.ux;
        xmin = fminf(xmin, x); xmax = fmaxf(xmax, x);
        ymin = fminf(ymin, y); ymax = fmaxf(ymax, y);
    }
    x0 = max(0, (int)floorf(xmin)); x1 = min(WW - 1, (int)ceilf(xmax));
    y0 = max(0, (int)floorf(ymin)); y1 = min(HH - 1, (int)ceilf(ymax));
}

// 256-thread block reduce, result broadcast; sm is float[4]
__device__ __forceinline__ float brb256(float v, float* sm) {
    #pragma unroll
    for (int off = 32; off > 0; off >>= 1) v += __shfl_down(v, off);
    const int lane = threadIdx.x & 63, wid = threadIdx.x >> 6;
    if (lane == 0) sm[wid] = v;
    __syncthreads();
    float r = sm[0] + sm[1] + sm[2] + sm[3];
    __syncthreads();
    return r;
}

// ---- K1: full-image copy (8 rows/block) + m_swept fused on copy registers --
__global__ __launch_bounds__(256)
void k_copy_mswept(const float* __restrict__ occ, const float* __restrict__ as,
                   const float* __restrict__ ae, float* __restrict__ out,
                   float* __restrict__ part1) {
    const int b = blockIdx.y, bx = blockIdx.x, tid = threadIdx.x;
    const float4* src = (const float4*)(occ + ((size_t)b << 20));
    float4*       dst = (float4*)(out + ((size_t)b << 20));
    // block bx owns rows [8*bx, 8*bx+8); thread t holds cols 4t..4t+3 of each row
    const int base4 = bx * 2048 + tid;       // + k*256 -> row 8*bx+k
    float4 v[8];
    #pragma unroll
    for (int k = 0; k < 8; k++) v[k] = src[base4 + k * 256];
    #pragma unroll
    for (int k = 0; k < 8; k++) dst[base4 + k * 256] = v[k];

    Geom g = load_geom(as, ae, b);
    int cx0, cx1, cy0, cy1; capsule_bbox(g, MARG, cx0, cx1, cy0, cy1);
    const int x = tid << 2;
    float sum = 0.f;
    if (x + 3 >= cx0 && x <= cx1) {
        #pragma unroll
        for (int k = 0; k < 8; k++) {
            const int y = bx * 8 + k;
            if (y >= cy0 && y <= cy1) {
                float fy = (float)y, fx = (float)x;
                sum += v[k].x * sweptf(g, fx + 0.f, fy);
                sum += v[k].y * sweptf(g, fx + 1.f, fy);
                sum += v[k].z * sweptf(g, fx + 2.f, fy);
                sum += v[k].w * sweptf(g, fx + 3.f, fy);
            }
        }
    }
    __shared__ float sm[4];
    float bs = brb256(sum, sm);
    if (tid == 0) part1[b * NB1 + bx] = bs;
}

// ---- K2: existing partials over probe strip bbox ---------------------------
__global__ __launch_bounds__(256)
void k_existing(const float* __restrict__ occ, const float* __restrict__ as,
                const float* __restrict__ ae, const float* __restrict__ part1,
                float* __restrict__ part2) {
    const int b = blockIdx.y, bx = blockIdx.x, tid = threadIdx.x;
    __shared__ float sm[4];
    const float m_swept = brb256((tid < NB1) ? part1[b * NB1 + tid] : 0.f, sm);
    const float pile = m_swept * (1.f / 6.f);

    Geom g = load_geom(as, ae, b);
    int x0, x1, y0, y1; strip_bbox(g, -MARG, pile + MARG, MARG, x0, x1, y0, y1);
    const float* base = occ + ((size_t)b << 20);
    float sum = 0.f;
    for (int y = y0 + bx; y <= y1; y += NB2) {
        float fy = (float)y;
        for (int x = x0 + tid; x <= x1; x += 256) {
            float s, lat; slat(g, (float)x, fy, s, lat);
            sum += base[((size_t)y << 10) + x] * sigf(s) * sigf(pile - s) * lat;
        }
    }
    float bs = brb256(sum, sm);
    if (tid == 0) part2[b * NB2 + bx] = bs;
}

// ---- K3: summask partials over dep strip bbox (no loads) -------------------
__global__ __launch_bounds__(256)
void k_summask(const float* __restrict__ as, const float* __restrict__ ae,
               const float* __restrict__ part1, const float* __restrict__ part2,
               float* __restrict__ part3) {
    const int b = blockIdx.y, bx = blockIdx.x, tid = threadIdx.x;
    __shared__ float sm[4];
    const float m_swept  = brb256((tid < NB1) ? part1[b * NB1 + tid] : 0.f, sm);
    const float existing = brb256((tid < NB2) ? part2[b * NB2 + tid] : 0.f, sm);
    const float pile  = m_swept * (1.f / 6.f);
    const float extra = existing * (1.f / 6.f);

    Geom g = load_geom(as, ae, b);
    int x0, x1, y0, y1; strip_bbox(g, extra - MARG, extra + pile + MARG, MARG, x0, x1, y0, y1);
    float sum = 0.f;
    for (int y = y0 + bx; y <= y1; y += NB2) {
        float fy = (float)y;
        for (int x = x0 + tid; x <= x1; x += 256) {
            float s, lat; slat(g, (float)x, fy, s, lat);
            sum += sigf(s - extra) * sigf(extra + pile - s) * lat;
        }
    }
    float bs = brb256(sum, sm);
    if (tid == 0) part3[b * NB2 + bx] = bs;
}

// ---- K4: patch union bbox: out = occ*(1-swept) + blur(dep), LDS blur -------
#define TH 8
#define TW 128
__global__ __launch_bounds__(256)
void k_patch(const float* __restrict__ occ, const float* __restrict__ as,
             const float* __restrict__ ae, const float* __restrict__ part1,
             const float* __restrict__ part2, const float* __restrict__ part3,
             float* __restrict__ out, BlurK wk) {
    const int b = blockIdx.y, bx = blockIdx.x, tid = threadIdx.x;
    __shared__ float sm[4];
    const float m_swept  = brb256((tid < NB1) ? part1[b * NB1 + tid] : 0.f, sm);
    const float existing = brb256((tid < NB2) ? part2[b * NB2 + tid] : 0.f, sm);
    const float summask  = brb256((tid < NB2) ? part3[b * NB2 + tid] : 0.f, sm);
    const float pile     = m_swept * (1.f / 6.f);
    const float extra    = existing * (1.f / 6.f);
    const float dep_norm = m_swept / (summask + EPSF);

    Geom g = load_geom(as, ae, b);
    int cx0, cx1, cy0, cy1; capsule_bbox(g, MARG, cx0, cx1, cy0, cy1);
    int sx0, sx1, sy0, sy1; strip_bbox(g, extra - MARG, extra + pile + MARG, MARG, sx0, sx1, sy0, sy1);
    const int ux0 = min(cx0, sx0), ux1 = max(cx1, sx1);
    const int uy0 = min(cy0, sy0), uy1 = max(cy1, sy1);
    const int bw = ux1 - ux0 + 1, bh = uy1 - uy0 + 1;
    const int ntx = (bw + TW - 1) / TW, nty = (bh + TH - 1) / TH;

    __shared__ float draw[TH + 2 * RAD][TW + 2 * RAD];
    __shared__ float hb[TH + 2 * RAD][TW];
    const float* ob = occ + ((size_t)b << 20);
    float* outb = out + ((size_t)b << 20);

    for (int t = bx; t < ntx * nty; t += NB2) {
        const int tx = t % ntx, ty = t / ntx;
        const int xt = ux0 + tx * TW, yt = uy0 + ty * TH;
        // dep with 4-px halo
        for (int i = tid; i < (TH + 8) * (TW + 8); i += 256) {
            int ly = i / (TW + 8), lx = i % (TW + 8);
            int gy = yt - RAD + ly, gx = xt - RAD + lx;
            float v = 0.f;
            if (gx >= 0 && gx < WW && gy >= 0 && gy < HH) {
                float s, lat; slat(g, (float)gx, (float)gy, s, lat);
                v = sigf(s - extra) * sigf(extra + pile - s) * lat * dep_norm;
            }
            draw[ly][lx] = v;
        }
        __syncthreads();
        // horizontal blur
        for (int i = tid; i < (TH + 8) * TW; i += 256) {
            int ly = i / TW, lx = i % TW;
            float acc = 0.f;
            #pragma unroll
            for (int j = 0; j < 9; j++) acc += wk.k[j] * draw[ly][lx + j];
            hb[ly][lx] = acc;
        }
        __syncthreads();
        // vertical blur + combine + store
        for (int i = tid; i < TH * TW; i += 256) {
            int ly = i / TW, lx = i % TW;
            int gy = yt + ly, gx = xt + lx;
            if (gy < HH && gx < WW) {
                float acc = 0.f;
                #pragma unroll
                for (int j = 0; j < 9; j++) acc += wk.k[j] * hb[ly + j][lx];
                size_t off = ((size_t)gy << 10) + gx;
                float o = ob[off];
                outb[off] = o * (1.f - sweptf(g, (float)gx, (float)gy)) + acc;
            }
        }
        __syncthreads();
    }
}

extern "C" void kernel_launch(void* const* d_in, const int* in_sizes, int n_in,
                              void* d_out, int out_size, void* d_ws, size_t ws_size,
                              hipStream_t stream) {
    const float* occ = (const float*)d_in[0];
    const float* as  = (const float*)d_in[1];
    const float* ae  = (const float*)d_in[2];
    float* out   = (float*)d_out;
    float* part1 = (float*)d_ws;                       // BB*NB1 floats
    float* part2 = part1 + BB * NB1;                   // BB*NB2 floats
    float* part3 = part2 + BB * NB2;                   // BB*NB2 floats

    BlurK wk;
    {
        float s = 0.f;
        for (int i = 0; i < 9; i++) {
            float t = (float)(i - RAD) / 1.5f;
            wk.k[i] = expf(-0.5f * t * t);
            s += wk.k[i];
        }
        for (int i = 0; i < 9; i++) wk.k[i] /= s;
    }

    k_copy_mswept<<<dim3(NB1, BB), 256, 0, stream>>>(occ, as, ae, out, part1);
    k_existing   <<<dim3(NB2, BB), 256, 0, stream>>>(occ, as, ae, part1, part2);
    k_summask    <<<dim3(NB2, BB), 256, 0, stream>>>(as, ae, part1, part2, part3);
    k_patch      <<<dim3(NB2, BB), 256, 0, stream>>>(occ, as, ae, part1, part2, part3, out, wk);
}